// Round 14
// baseline (77.525 us; speedup 1.0000x reference)
//
#include <hip/hip_runtime.h>
#include <hip/hip_bf16.h>

#define BB 4
#define CC 64
#define DD 8
#define NN 32768
#define WW 512
#define STR 256
#define NWIN 127
#define LOG2E 1.4426950408889634f

typedef short bf16x8 __attribute__((ext_vector_type(8)));
typedef float f32x4 __attribute__((ext_vector_type(4)));
typedef float f32x16 __attribute__((ext_vector_type(16)));

__device__ __forceinline__ unsigned int pack_bf16(float lo, float hi) {
    __hip_bfloat162 h = __float22bfloat162_rn(make_float2(lo, hi));  // v_cvt_pk_bf16_f32
    unsigned int r; __builtin_memcpy(&r, &h, 4);
    return r;
}
__device__ __forceinline__ unsigned short to_bf16(float f) {
    __hip_bfloat16 h = __float2bfloat16(f);
    unsigned short r; __builtin_memcpy(&r, &h, 2);
    return r;
}
__device__ __forceinline__ float bf2f(unsigned short s) {
    union { unsigned int u; float f; } v; v.u = ((unsigned int)s) << 16;
    return v.f;
}
// guaranteed single v_exp_f32 (exp2f() is an ocml expansion)
__device__ __forceinline__ float fast_exp2(float x) {
#if __has_builtin(__builtin_amdgcn_exp2f)
    return __builtin_amdgcn_exp2f(x);
#else
    float r; asm("v_exp_f32 %0, %1" : "=v"(r) : "v"(x)); return r;
#endif
}
// swap upper 32 lanes of x with lower 32 lanes of y (gfx950)
__device__ __forceinline__ void plswap(unsigned int &x, unsigned int &y) {
    asm("v_permlane32_swap_b32 %0, %1" : "+v"(x), "+v"(y));
}
__device__ __forceinline__ bf16x8 pack8(float a0, float a1, float a2, float a3,
                                        float a4, float a5, float a6, float a7) {
    union { bf16x8 v; unsigned int u[4]; } r;
    r.u[0] = pack_bf16(a0, a1); r.u[1] = pack_bf16(a2, a3);
    r.u[2] = pack_bf16(a4, a5); r.u[3] = pack_bf16(a6, a7);
    return r.v;
}
__device__ __forceinline__ bf16x8 words4(unsigned int w0, unsigned int w1,
                                         unsigned int w2, unsigned int w3) {
    union { bf16x8 v; unsigned int u[4]; } r;
    r.u[0] = w0; r.u[1] = w1; r.u[2] = w2; r.u[3] = w3;
    return r.v;
}

// Tiled bf16 layout for V and acc buffers:
//   elem addr = ((b*1024 + (n>>5))*4 + ((n>>3)&3))*512 + c*8 + (n&7)
// -> an MFMA B-frag read (fixed n-octet across 32 c's) is 512B contiguous.

// ---------------- kernel 1: QKV projection as MFMA GEMM ----------------
__global__ __launch_bounds__(256) void qkv_kernel(
    const float* __restrict__ x,
    const float* __restrict__ Wq, const float* __restrict__ bq,
    const float* __restrict__ Wk, const float* __restrict__ bk,
    const float* __restrict__ Wv, const float* __restrict__ bv,
    unsigned short* __restrict__ qout, unsigned short* __restrict__ kout,
    unsigned short* __restrict__ vout)
{
    const int t = threadIdx.x;
    const int lane = t & 63, wv = t >> 6;
    const int a = lane & 15, g = lane >> 4;

    bf16x8 wf[5][2];
    #pragma unroll
    for (int T = 0; T < 5; ++T) {
        const float* wrow;
        float scale = 1.f;
        if (T == 0) {
            if (a < 8) { wrow = Wq + a*CC; scale = LOG2E; }
            else       { wrow = Wk + (a-8)*CC; }
        } else {
            wrow = Wv + ((T-1)*16 + a)*CC;
        }
        #pragma unroll
        for (int h = 0; h < 2; ++h) {
            float4 w0 = *(const float4*)(wrow + h*32 + g*8);
            float4 w1 = *(const float4*)(wrow + h*32 + g*8 + 4);
            wf[T][h] = pack8(w0.x*scale, w0.y*scale, w0.z*scale, w0.w*scale,
                             w1.x*scale, w1.y*scale, w1.z*scale, w1.w*scale);
        }
    }
    f32x4 bias[5];
    {
        const int r = g*4;
        #pragma unroll
        for (int u = 0; u < 4; ++u) {
            int rr = r + u;
            bias[0][u] = (rr < 8) ? bq[rr]*LOG2E : bk[rr-8];
        }
        #pragma unroll
        for (int T = 1; T < 5; ++T)
            #pragma unroll
            for (int u = 0; u < 4; ++u)
                bias[T][u] = bv[(T-1)*16 + r + u];
    }

    const int wave_id = blockIdx.x*4 + wv;
    #pragma unroll 1
    for (int it = 0; it < 2; ++it) {
        const int chunk = wave_id + it*4096;
        const int b = chunk >> 11;
        const int n0 = (chunk & 2047) * 16;
        const int n = n0 + a;
        const float* xcol = x + (size_t)b*CC*NN + n;

        float xv0[8], xv1[8];
        #pragma unroll
        for (int u = 0; u < 8; ++u) xv0[u] = xcol[(size_t)(g*8 + u)*NN];
        #pragma unroll
        for (int u = 0; u < 8; ++u) xv1[u] = xcol[(size_t)(32 + g*8 + u)*NN];
        bf16x8 xb0 = pack8(xv0[0],xv0[1],xv0[2],xv0[3],xv0[4],xv0[5],xv0[6],xv0[7]);
        bf16x8 xb1 = pack8(xv1[0],xv1[1],xv1[2],xv1[3],xv1[4],xv1[5],xv1[6],xv1[7]);

        f32x4 acc[5];
        #pragma unroll
        for (int T = 0; T < 5; ++T) {
            acc[T] = __builtin_amdgcn_mfma_f32_16x16x32_bf16(wf[T][0], xb0, bias[T], 0, 0, 0);
            acc[T] = __builtin_amdgcn_mfma_f32_16x16x32_bf16(wf[T][1], xb1, acc[T], 0, 0, 0);
        }

        {
            unsigned int lo = pack_bf16(acc[0][0], acc[0][1]);
            unsigned int hi = pack_bf16(acc[0][2], acc[0][3]);
            unsigned short* base = ((g < 2) ? qout : kout) + ((size_t)b*NN + n)*8 + (g & 1)*4;
            *(int2*)base = make_int2((int)lo, (int)hi);
        }
        // v: tiled layout [b][n>>5][(n>>3)&3][c][n&7]
        unsigned short* vtb = vout + (((size_t)b*1024 + (n>>5))*4 + ((n>>3)&3))*512 + (n&7);
        #pragma unroll
        for (int T = 1; T < 5; ++T) {
            #pragma unroll
            for (int u = 0; u < 4; ++u) {
                const int e = (T-1)*16 + g*4 + u;
                vtb[e*8] = to_bf16(acc[T][u]);
            }
        }
    }
}

// ---------------- kernel 2: windowed attention, 32x32x16 MFMA ----------------
// Wave = 32 i x 64 c; block = 4 independent waves (128-i window quarter).
// NO LDS staging, NO __syncthreads: V/K/Q frags come straight from global in
// fully-coalesced form (V tiled layout -> 512B/instr; K rows [n][8] -> 512B).
// K/V prefetched 1 jt deep; #pragma unroll 2 renames prefetch regs (no movs).
// Output stores use the same tiled layout (8 transactions/instr instead of 32).
__global__ __launch_bounds__(256) void attn_kernel(
    const unsigned short* __restrict__ qg, const unsigned short* __restrict__ kg,
    const unsigned short* __restrict__ vg,
    unsigned short* __restrict__ accE, unsigned short* __restrict__ accO)
{
    __shared__ float sInv[4][32];
    const int t = threadIdx.x;
    const int lane = t & 63, wv = t >> 6;
    const int l31 = lane & 31, hi = lane >> 5;
    int bid = (blockIdx.x & 7)*254 + (blockIdx.x >> 3);   // XCD bijective swizzle (8x254)
    const int q2 = bid & 3; bid >>= 2;                    // window quarter (128 i)
    const int w = bid % NWIN, b = bid / NWIN;
    const int nwin = STR * w;
    const int i0 = q2*128 + wv*32;

    const unsigned short* qbase = qg + ((size_t)b*NN + nwin + i0)*8;
    const unsigned short* kbase = kg + ((size_t)b*NN + nwin)*8;
    // V frag (ct, sl) at tile jt: vt + (jt*4 + sl*2)*512 + ct*256
    const unsigned short* vt = vg + (((size_t)b*1024 + 8*w)*4 + 2*hi)*512 + (size_t)l31*8;

    const bf16x8 zf = {};
    // Q B-frag: col i = l31, k = d = 8*hi+e; hi half zeroed (d-pad annihilates)
    bf16x8 qf;
    {
        bf16x8 raw = *(const bf16x8*)(qbase + (size_t)l31*8);
        qf = hi ? zf : raw;
    }

    f32x16 acc[2] = {};    // [ct]
    float2 rsum2 = make_float2(0.f, 0.f);

    // prefetch jt=0 K + V frags
    bf16x8 kc = *(const bf16x8*)(kbase + (size_t)l31*8);
    bf16x8 vc[2][2];
    #pragma unroll
    for (int ct = 0; ct < 2; ++ct)
        #pragma unroll
        for (int sl = 0; sl < 2; ++sl)
            vc[ct][sl] = *(const bf16x8*)(vt + (size_t)(sl*2)*512 + ct*256);

    #pragma unroll 2
    for (int jt = 0; jt < 16; ++jt) {
        // prefetch next tile's K + V (renamed by unroll; no rotation movs)
        bf16x8 kn = kc;
        bf16x8 vn[2][2] = {{vc[0][0], vc[0][1]}, {vc[1][0], vc[1][1]}};
        if (jt < 15) {
            kn = *(const bf16x8*)(kbase + (size_t)(jt*32 + 32 + l31)*8);
            #pragma unroll
            for (int ct = 0; ct < 2; ++ct)
                #pragma unroll
                for (int sl = 0; sl < 2; ++sl)
                    vn[ct][sl] = *(const bf16x8*)(vt + (size_t)((jt+1)*4 + sl*2)*512 + ct*256);
        }

        const f32x16 z16 = {};
        f32x16 E = __builtin_amdgcn_mfma_f32_32x32x16_bf16(kc, qf, z16, 0, 0, 0);
        float p[16];
        #pragma unroll
        for (int r = 0; r < 16; ++r) p[r] = fast_exp2(E[r]);
        float2 s0 = make_float2(p[0],  p[1])  + make_float2(p[2],  p[3]);
        float2 s1 = make_float2(p[4],  p[5])  + make_float2(p[6],  p[7]);
        float2 s2 = make_float2(p[8],  p[9])  + make_float2(p[10], p[11]);
        float2 s3 = make_float2(p[12], p[13]) + make_float2(p[14], p[15]);
        rsum2 += (s0 + s1) + (s2 + s3);
        unsigned int wd[8];
        #pragma unroll
        for (int tw = 0; tw < 8; ++tw) wd[tw] = pack_bf16(p[2*tw], p[2*tw+1]);
        unsigned int F0 = wd[0], F2 = wd[2]; plswap(F0, F2);
        unsigned int F1 = wd[1], F3 = wd[3]; plswap(F1, F3);
        unsigned int G0 = wd[4], G2 = wd[6]; plswap(G0, G2);
        unsigned int G1 = wd[5], G3 = wd[7]; plswap(G1, G3);
        bf16x8 pa0 = words4(F0, F1, F2, F3);   // k-slab j+0..15
        bf16x8 pa1 = words4(G0, G1, G2, G3);   // k-slab j+16..31
        #pragma unroll
        for (int ct = 0; ct < 2; ++ct) {
            acc[ct] = __builtin_amdgcn_mfma_f32_32x32x16_bf16(pa0, vc[ct][0], acc[ct], 0, 0, 0);
            acc[ct] = __builtin_amdgcn_mfma_f32_32x32x16_bf16(pa1, vc[ct][1], acc[ct], 0, 0, 0);
        }
        kc = kn;
        #pragma unroll
        for (int ct = 0; ct < 2; ++ct)
            #pragma unroll
            for (int sl = 0; sl < 2; ++sl)
                vc[ct][sl] = vn[ct][sl];
    }

    // ---- normalization: combine hi/lo j-halves, broadcast 1/r via LDS ----
    float r = rsum2.x + rsum2.y;
    r += __shfl_xor(r, 32);
    if (lane < 32) sInv[wv][lane] = 1.f / r;
    f32x4 invv[4];
    #pragma unroll
    for (int g = 0; g < 4; ++g)
        invv[g] = *(const f32x4*)&sInv[wv][8*g + 4*hi];

    // tiled store: i_local = u + 8*g + 4*hi -> addr = (Tb + g)*512 + c*8 + 4*hi + u
    unsigned short* ob = ((w & 1) ? accO : accE)
        + ((size_t)b*1024 + ((nwin + i0) >> 5))*4*512 + 4*hi;
    #pragma unroll
    for (int ct = 0; ct < 2; ++ct) {
        unsigned short* cbase = ob + (ct*32 + l31)*8;
        #pragma unroll
        for (int g = 0; g < 4; ++g) {
            float a0 = acc[ct][4*g+0] * invv[g][0];
            float a1 = acc[ct][4*g+1] * invv[g][1];
            float a2 = acc[ct][4*g+2] * invv[g][2];
            float a3 = acc[ct][4*g+3] * invv[g][3];
            int2 pw = make_int2((int)pack_bf16(a0, a1), (int)pack_bf16(a2, a3));
            *(int2*)(cbase + (size_t)g*512) = pw;
        }
    }
}

// ---------------- kernel 3: combine + 2:1 maxpool ----------------
__global__ __launch_bounds__(256) void final_kernel(
    const float* __restrict__ x,
    const unsigned short* __restrict__ accE, const unsigned short* __restrict__ accO,
    const float* __restrict__ gamma, float* __restrict__ out)
{
    const size_t tid = (size_t)blockIdx.x*256 + threadIdx.x;  // B*C*N/8 threads
    const size_t base = tid*8;                                 // logical [b][c][n]
    const int n = (int)(base & (NN-1));
    const int c = (int)((base >> 15) & (CC-1));
    const int b = (int)(base >> 21);
    const float g = gamma[0];
    // tiled acc address for (b, c, n..n+7)
    const size_t tadr = (((size_t)b*1024 + (n >> 5))*4 + ((n >> 3) & 3))*512 + c*8;

    float xv[8];
    *(float4*)&xv[0] = *(const float4*)&x[base];
    *(float4*)&xv[4] = *(const float4*)&x[base+4];
    int4 aeq = *(const int4*)&accE[tadr];
    const unsigned int* ae = (const unsigned int*)&aeq;

    float s[8];
    if (n >= STR && n < NN - STR) {
        int4 aoq = *(const int4*)&accO[tadr];
        const unsigned int* ao = (const unsigned int*)&aoq;
        #pragma unroll
        for (int u = 0; u < 4; ++u) {
            float e0 = bf2f((unsigned short)(ae[u] & 0xffff));
            float e1 = bf2f((unsigned short)(ae[u] >> 16));
            float o0 = bf2f((unsigned short)(ao[u] & 0xffff));
            float o1 = bf2f((unsigned short)(ao[u] >> 16));
            s[2*u]   = fmaf(g, (e0 + o0)*0.5f, xv[2*u]);
            s[2*u+1] = fmaf(g, (e1 + o1)*0.5f, xv[2*u+1]);
        }
    } else {
        #pragma unroll
        for (int u = 0; u < 4; ++u) {
            float e0 = bf2f((unsigned short)(ae[u] & 0xffff));
            float e1 = bf2f((unsigned short)(ae[u] >> 16));
            s[2*u]   = fmaf(g, e0, xv[2*u]);
            s[2*u+1] = fmaf(g, e1, xv[2*u+1]);
        }
    }
    float4 o = make_float4(fmaxf(s[0], s[1]), fmaxf(s[2], s[3]),
                           fmaxf(s[4], s[5]), fmaxf(s[6], s[7]));
    *(float4*)&out[tid*4] = o;
}

extern "C" void kernel_launch(void* const* d_in, const int* in_sizes, int n_in,
                              void* d_out, int out_size, void* d_ws, size_t ws_size,
                              hipStream_t stream)
{
    const float* x    = (const float*)d_in[0];
    const float* Wq   = (const float*)d_in[1];
    const float* bq   = (const float*)d_in[2];
    const float* Wk   = (const float*)d_in[3];
    const float* bk   = (const float*)d_in[4];
    const float* Wv   = (const float*)d_in[5];
    const float* bv   = (const float*)d_in[6];
    const float* gamma= (const float*)d_in[7];

    unsigned short* q    = (unsigned short*)d_ws;
    unsigned short* k    = q + (size_t)BB*NN*DD;
    unsigned short* v    = k + (size_t)BB*NN*DD;
    unsigned short* accE = v + (size_t)BB*CC*NN;
    unsigned short* accO = accE + (size_t)BB*CC*NN;
    float* out = (float*)d_out;

    qkv_kernel<<<1024, 256, 0, stream>>>(x, Wq, bq, Wk, bk, Wv, bv, q, k, v);
    attn_kernel<<<BB*NWIN*4, 256, 0, stream>>>(q, k, v, accE, accO);
    final_kernel<<<BB*CC*NN/8/256, 256, 0, stream>>>(x, accE, accO, gamma, out);
}

// Round 15
// 77.386 us; speedup vs baseline: 1.0018x; 1.0018x over previous
//
#include <hip/hip_runtime.h>
#include <hip/hip_bf16.h>

#define BB 4
#define CC 64
#define DD 8
#define NN 32768
#define WW 512
#define STR 256
#define NWIN 127
#define LOG2E 1.4426950408889634f

typedef short bf16x8 __attribute__((ext_vector_type(8)));
typedef float f32x4 __attribute__((ext_vector_type(4)));
typedef float f32x16 __attribute__((ext_vector_type(16)));

__device__ __forceinline__ unsigned int pack_bf16(float lo, float hi) {
    __hip_bfloat162 h = __float22bfloat162_rn(make_float2(lo, hi));  // v_cvt_pk_bf16_f32
    unsigned int r; __builtin_memcpy(&r, &h, 4);
    return r;
}
__device__ __forceinline__ unsigned short to_bf16(float f) {
    __hip_bfloat16 h = __float2bfloat16(f);
    unsigned short r; __builtin_memcpy(&r, &h, 2);
    return r;
}
__device__ __forceinline__ float bf2f(unsigned short s) {
    union { unsigned int u; float f; } v; v.u = ((unsigned int)s) << 16;
    return v.f;
}
// guaranteed single v_exp_f32 (exp2f() is an ocml expansion)
__device__ __forceinline__ float fast_exp2(float x) {
#if __has_builtin(__builtin_amdgcn_exp2f)
    return __builtin_amdgcn_exp2f(x);
#else
    float r; asm("v_exp_f32 %0, %1" : "=v"(r) : "v"(x)); return r;
#endif
}
// swap upper 32 lanes of x with lower 32 lanes of y (gfx950)
__device__ __forceinline__ void plswap(unsigned int &x, unsigned int &y) {
    asm("v_permlane32_swap_b32 %0, %1" : "+v"(x), "+v"(y));
}
__device__ __forceinline__ bf16x8 pack8(float a0, float a1, float a2, float a3,
                                        float a4, float a5, float a6, float a7) {
    union { bf16x8 v; unsigned int u[4]; } r;
    r.u[0] = pack_bf16(a0, a1); r.u[1] = pack_bf16(a2, a3);
    r.u[2] = pack_bf16(a4, a5); r.u[3] = pack_bf16(a6, a7);
    return r.v;
}
__device__ __forceinline__ bf16x8 words4(unsigned int w0, unsigned int w1,
                                         unsigned int w2, unsigned int w3) {
    union { bf16x8 v; unsigned int u[4]; } r;
    r.u[0] = w0; r.u[1] = w1; r.u[2] = w2; r.u[3] = w3;
    return r.v;
}

// Tiled bf16 layout for V and acc buffers:
//   elem addr = ((b*1024 + (n>>5))*4 + ((n>>3)&3))*512 + c*8 + (n&7)
// -> an MFMA B-frag read (fixed n-octet across 32 c's) is 512B contiguous.

// ---------------- kernel 1: QKV projection as MFMA GEMM ----------------
__global__ __launch_bounds__(256) void qkv_kernel(
    const float* __restrict__ x,
    const float* __restrict__ Wq, const float* __restrict__ bq,
    const float* __restrict__ Wk, const float* __restrict__ bk,
    const float* __restrict__ Wv, const float* __restrict__ bv,
    unsigned short* __restrict__ qout, unsigned short* __restrict__ kout,
    unsigned short* __restrict__ vout)
{
    const int t = threadIdx.x;
    const int lane = t & 63, wv = t >> 6;
    const int a = lane & 15, g = lane >> 4;

    bf16x8 wf[5][2];
    #pragma unroll
    for (int T = 0; T < 5; ++T) {
        const float* wrow;
        float scale = 1.f;
        if (T == 0) {
            if (a < 8) { wrow = Wq + a*CC; scale = LOG2E; }
            else       { wrow = Wk + (a-8)*CC; }
        } else {
            wrow = Wv + ((T-1)*16 + a)*CC;
        }
        #pragma unroll
        for (int h = 0; h < 2; ++h) {
            float4 w0 = *(const float4*)(wrow + h*32 + g*8);
            float4 w1 = *(const float4*)(wrow + h*32 + g*8 + 4);
            wf[T][h] = pack8(w0.x*scale, w0.y*scale, w0.z*scale, w0.w*scale,
                             w1.x*scale, w1.y*scale, w1.z*scale, w1.w*scale);
        }
    }
    f32x4 bias[5];
    {
        const int r = g*4;
        #pragma unroll
        for (int u = 0; u < 4; ++u) {
            int rr = r + u;
            bias[0][u] = (rr < 8) ? bq[rr]*LOG2E : bk[rr-8];
        }
        #pragma unroll
        for (int T = 1; T < 5; ++T)
            #pragma unroll
            for (int u = 0; u < 4; ++u)
                bias[T][u] = bv[(T-1)*16 + r + u];
    }

    const int wave_id = blockIdx.x*4 + wv;
    #pragma unroll 1
    for (int it = 0; it < 2; ++it) {
        const int chunk = wave_id + it*4096;
        const int b = chunk >> 11;
        const int n0 = (chunk & 2047) * 16;
        const int n = n0 + a;
        const float* xcol = x + (size_t)b*CC*NN + n;

        float xv0[8], xv1[8];
        #pragma unroll
        for (int u = 0; u < 8; ++u) xv0[u] = xcol[(size_t)(g*8 + u)*NN];
        #pragma unroll
        for (int u = 0; u < 8; ++u) xv1[u] = xcol[(size_t)(32 + g*8 + u)*NN];
        bf16x8 xb0 = pack8(xv0[0],xv0[1],xv0[2],xv0[3],xv0[4],xv0[5],xv0[6],xv0[7]);
        bf16x8 xb1 = pack8(xv1[0],xv1[1],xv1[2],xv1[3],xv1[4],xv1[5],xv1[6],xv1[7]);

        f32x4 acc[5];
        #pragma unroll
        for (int T = 0; T < 5; ++T) {
            acc[T] = __builtin_amdgcn_mfma_f32_16x16x32_bf16(wf[T][0], xb0, bias[T], 0, 0, 0);
            acc[T] = __builtin_amdgcn_mfma_f32_16x16x32_bf16(wf[T][1], xb1, acc[T], 0, 0, 0);
        }

        {
            unsigned int lo = pack_bf16(acc[0][0], acc[0][1]);
            unsigned int hi = pack_bf16(acc[0][2], acc[0][3]);
            unsigned short* base = ((g < 2) ? qout : kout) + ((size_t)b*NN + n)*8 + (g & 1)*4;
            *(int2*)base = make_int2((int)lo, (int)hi);
        }
        // v: tiled layout [b][n>>5][(n>>3)&3][c][n&7]
        unsigned short* vtb = vout + (((size_t)b*1024 + (n>>5))*4 + ((n>>3)&3))*512 + (n&7);
        #pragma unroll
        for (int T = 1; T < 5; ++T) {
            #pragma unroll
            for (int u = 0; u < 4; ++u) {
                const int e = (T-1)*16 + g*4 + u;
                vtb[e*8] = to_bf16(acc[T][u]);
            }
        }
    }
}

// ---------------- kernel 2: windowed attention, 32x32x16 MFMA ----------------
// EXPERIMENT: 2-wave blocks (128 thr), grid 4064 = 8 x 508, ZERO LDS, no barriers.
// Wave = 32 i x 64 c, fully independent scheduling units; 1/rsum broadcast via
// __shfl instead of LDS. Everything else = R14 (tiled V, 1-deep K/V prefetch).
__global__ __launch_bounds__(128) void attn_kernel(
    const unsigned short* __restrict__ qg, const unsigned short* __restrict__ kg,
    const unsigned short* __restrict__ vg,
    unsigned short* __restrict__ accE, unsigned short* __restrict__ accO)
{
    const int t = threadIdx.x;
    const int lane = t & 63, wv = t >> 6;
    const int l31 = lane & 31, hi = lane >> 5;
    int bid = (blockIdx.x & 7)*508 + (blockIdx.x >> 3);   // XCD bijective swizzle (8x508)
    const int oct = bid & 7; bid >>= 3;                   // 8 blocks per window
    const int w = bid % NWIN, b = bid / NWIN;
    const int nwin = STR * w;
    const int i0 = oct*64 + wv*32;

    const unsigned short* qbase = qg + ((size_t)b*NN + nwin + i0)*8;
    const unsigned short* kbase = kg + ((size_t)b*NN + nwin)*8;
    // V frag (ct, sl) at tile jt: vt + (jt*4 + sl*2)*512 + ct*256
    const unsigned short* vt = vg + (((size_t)b*1024 + 8*w)*4 + 2*hi)*512 + (size_t)l31*8;

    const bf16x8 zf = {};
    // Q B-frag: col i = l31, k = d = 8*hi+e; hi half zeroed (d-pad annihilates)
    bf16x8 qf;
    {
        bf16x8 raw = *(const bf16x8*)(qbase + (size_t)l31*8);
        qf = hi ? zf : raw;
    }

    f32x16 acc[2] = {};    // [ct]
    float2 rsum2 = make_float2(0.f, 0.f);

    // prefetch jt=0 K + V frags
    bf16x8 kc = *(const bf16x8*)(kbase + (size_t)l31*8);
    bf16x8 vc[2][2];
    #pragma unroll
    for (int ct = 0; ct < 2; ++ct)
        #pragma unroll
        for (int sl = 0; sl < 2; ++sl)
            vc[ct][sl] = *(const bf16x8*)(vt + (size_t)(sl*2)*512 + ct*256);

    #pragma unroll 2
    for (int jt = 0; jt < 16; ++jt) {
        // prefetch next tile's K + V (renamed by unroll; no rotation movs)
        bf16x8 kn = kc;
        bf16x8 vn[2][2] = {{vc[0][0], vc[0][1]}, {vc[1][0], vc[1][1]}};
        if (jt < 15) {
            kn = *(const bf16x8*)(kbase + (size_t)(jt*32 + 32 + l31)*8);
            #pragma unroll
            for (int ct = 0; ct < 2; ++ct)
                #pragma unroll
                for (int sl = 0; sl < 2; ++sl)
                    vn[ct][sl] = *(const bf16x8*)(vt + (size_t)((jt+1)*4 + sl*2)*512 + ct*256);
        }

        const f32x16 z16 = {};
        f32x16 E = __builtin_amdgcn_mfma_f32_32x32x16_bf16(kc, qf, z16, 0, 0, 0);
        float p[16];
        #pragma unroll
        for (int r = 0; r < 16; ++r) p[r] = fast_exp2(E[r]);
        float2 s0 = make_float2(p[0],  p[1])  + make_float2(p[2],  p[3]);
        float2 s1 = make_float2(p[4],  p[5])  + make_float2(p[6],  p[7]);
        float2 s2 = make_float2(p[8],  p[9])  + make_float2(p[10], p[11]);
        float2 s3 = make_float2(p[12], p[13]) + make_float2(p[14], p[15]);
        rsum2 += (s0 + s1) + (s2 + s3);
        unsigned int wd[8];
        #pragma unroll
        for (int tw = 0; tw < 8; ++tw) wd[tw] = pack_bf16(p[2*tw], p[2*tw+1]);
        unsigned int F0 = wd[0], F2 = wd[2]; plswap(F0, F2);
        unsigned int F1 = wd[1], F3 = wd[3]; plswap(F1, F3);
        unsigned int G0 = wd[4], G2 = wd[6]; plswap(G0, G2);
        unsigned int G1 = wd[5], G3 = wd[7]; plswap(G1, G3);
        bf16x8 pa0 = words4(F0, F1, F2, F3);   // k-slab j+0..15
        bf16x8 pa1 = words4(G0, G1, G2, G3);   // k-slab j+16..31
        #pragma unroll
        for (int ct = 0; ct < 2; ++ct) {
            acc[ct] = __builtin_amdgcn_mfma_f32_32x32x16_bf16(pa0, vc[ct][0], acc[ct], 0, 0, 0);
            acc[ct] = __builtin_amdgcn_mfma_f32_32x32x16_bf16(pa1, vc[ct][1], acc[ct], 0, 0, 0);
        }
        kc = kn;
        #pragma unroll
        for (int ct = 0; ct < 2; ++ct)
            #pragma unroll
            for (int sl = 0; sl < 2; ++sl)
                vc[ct][sl] = vn[ct][sl];
    }

    // ---- normalization: combine hi/lo j-halves; broadcast 1/r via shfl (no LDS) ----
    float r = rsum2.x + rsum2.y;
    r += __shfl_xor(r, 32);
    const float inv = 1.f / r;            // lane's own col i = l31
    f32x4 invv[4];
    #pragma unroll
    for (int g = 0; g < 4; ++g)
        #pragma unroll
        for (int u = 0; u < 4; ++u)
            invv[g][u] = __shfl(inv, 8*g + 4*hi + u);

    // tiled store: i_local = u + 8*g + 4*hi -> addr = (Tb + g)*512 + c*8 + 4*hi + u
    unsigned short* ob = ((w & 1) ? accO : accE)
        + ((size_t)b*1024 + ((nwin + i0) >> 5))*4*512 + 4*hi;
    #pragma unroll
    for (int ct = 0; ct < 2; ++ct) {
        unsigned short* cbase = ob + (ct*32 + l31)*8;
        #pragma unroll
        for (int g = 0; g < 4; ++g) {
            float a0 = acc[ct][4*g+0] * invv[g][0];
            float a1 = acc[ct][4*g+1] * invv[g][1];
            float a2 = acc[ct][4*g+2] * invv[g][2];
            float a3 = acc[ct][4*g+3] * invv[g][3];
            int2 pw = make_int2((int)pack_bf16(a0, a1), (int)pack_bf16(a2, a3));
            *(int2*)(cbase + (size_t)g*512) = pw;
        }
    }
}

// ---------------- kernel 3: combine + 2:1 maxpool ----------------
__global__ __launch_bounds__(256) void final_kernel(
    const float* __restrict__ x,
    const unsigned short* __restrict__ accE, const unsigned short* __restrict__ accO,
    const float* __restrict__ gamma, float* __restrict__ out)
{
    const size_t tid = (size_t)blockIdx.x*256 + threadIdx.x;  // B*C*N/8 threads
    const size_t base = tid*8;                                 // logical [b][c][n]
    const int n = (int)(base & (NN-1));
    const int c = (int)((base >> 15) & (CC-1));
    const int b = (int)(base >> 21);
    const float g = gamma[0];
    // tiled acc address for (b, c, n..n+7)
    const size_t tadr = (((size_t)b*1024 + (n >> 5))*4 + ((n >> 3) & 3))*512 + c*8;

    float xv[8];
    *(float4*)&xv[0] = *(const float4*)&x[base];
    *(float4*)&xv[4] = *(const float4*)&x[base+4];
    int4 aeq = *(const int4*)&accE[tadr];
    const unsigned int* ae = (const unsigned int*)&aeq;

    float s[8];
    if (n >= STR && n < NN - STR) {
        int4 aoq = *(const int4*)&accO[tadr];
        const unsigned int* ao = (const unsigned int*)&aoq;
        #pragma unroll
        for (int u = 0; u < 4; ++u) {
            float e0 = bf2f((unsigned short)(ae[u] & 0xffff));
            float e1 = bf2f((unsigned short)(ae[u] >> 16));
            float o0 = bf2f((unsigned short)(ao[u] & 0xffff));
            float o1 = bf2f((unsigned short)(ao[u] >> 16));
            s[2*u]   = fmaf(g, (e0 + o0)*0.5f, xv[2*u]);
            s[2*u+1] = fmaf(g, (e1 + o1)*0.5f, xv[2*u+1]);
        }
    } else {
        #pragma unroll
        for (int u = 0; u < 4; ++u) {
            float e0 = bf2f((unsigned short)(ae[u] & 0xffff));
            float e1 = bf2f((unsigned short)(ae[u] >> 16));
            s[2*u]   = fmaf(g, e0, xv[2*u]);
            s[2*u+1] = fmaf(g, e1, xv[2*u+1]);
        }
    }
    float4 o = make_float4(fmaxf(s[0], s[1]), fmaxf(s[2], s[3]),
                           fmaxf(s[4], s[5]), fmaxf(s[6], s[7]));
    *(float4*)&out[tid*4] = o;
}

extern "C" void kernel_launch(void* const* d_in, const int* in_sizes, int n_in,
                              void* d_out, int out_size, void* d_ws, size_t ws_size,
                              hipStream_t stream)
{
    const float* x    = (const float*)d_in[0];
    const float* Wq   = (const float*)d_in[1];
    const float* bq   = (const float*)d_in[2];
    const float* Wk   = (const float*)d_in[3];
    const float* bk   = (const float*)d_in[4];
    const float* Wv   = (const float*)d_in[5];
    const float* bv   = (const float*)d_in[6];
    const float* gamma= (const float*)d_in[7];

    unsigned short* q    = (unsigned short*)d_ws;
    unsigned short* k    = q + (size_t)BB*NN*DD;
    unsigned short* v    = k + (size_t)BB*NN*DD;
    unsigned short* accE = v + (size_t)BB*CC*NN;
    unsigned short* accO = accE + (size_t)BB*CC*NN;
    float* out = (float*)d_out;

    qkv_kernel<<<1024, 256, 0, stream>>>(x, Wq, bq, Wk, bk, Wv, bv, q, k, v);
    attn_kernel<<<BB*NWIN*8, 128, 0, stream>>>(q, k, v, accE, accO);
    final_kernel<<<BB*CC*NN/8/256, 256, 0, stream>>>(x, accE, accO, gamma, out);
}

// Round 16
// 71.902 us; speedup vs baseline: 1.0782x; 1.0763x over previous
//
#include <hip/hip_runtime.h>
#include <hip/hip_bf16.h>

#define BB 4
#define CC 64
#define DD 8
#define NN 32768
#define WW 512
#define STR 256
#define NWIN 127
#define LOG2E 1.4426950408889634f

typedef short bf16x8 __attribute__((ext_vector_type(8)));
typedef float f32x4 __attribute__((ext_vector_type(4)));
typedef float f32x16 __attribute__((ext_vector_type(16)));

__device__ __forceinline__ unsigned int pack_bf16(float lo, float hi) {
    __hip_bfloat162 h = __float22bfloat162_rn(make_float2(lo, hi));  // v_cvt_pk_bf16_f32
    unsigned int r; __builtin_memcpy(&r, &h, 4);
    return r;
}
__device__ __forceinline__ unsigned short to_bf16(float f) {
    __hip_bfloat16 h = __float2bfloat16(f);
    unsigned short r; __builtin_memcpy(&r, &h, 2);
    return r;
}
__device__ __forceinline__ float bf2f(unsigned short s) {
    union { unsigned int u; float f; } v; v.u = ((unsigned int)s) << 16;
    return v.f;
}
// guaranteed single v_exp_f32 (exp2f() is an ocml expansion)
__device__ __forceinline__ float fast_exp2(float x) {
#if __has_builtin(__builtin_amdgcn_exp2f)
    return __builtin_amdgcn_exp2f(x);
#else
    float r; asm("v_exp_f32 %0, %1" : "=v"(r) : "v"(x)); return r;
#endif
}
// swap upper 32 lanes of x with lower 32 lanes of y (gfx950)
__device__ __forceinline__ void plswap(unsigned int &x, unsigned int &y) {
    asm("v_permlane32_swap_b32 %0, %1" : "+v"(x), "+v"(y));
}
__device__ __forceinline__ bf16x8 pack8(float a0, float a1, float a2, float a3,
                                        float a4, float a5, float a6, float a7) {
    union { bf16x8 v; unsigned int u[4]; } r;
    r.u[0] = pack_bf16(a0, a1); r.u[1] = pack_bf16(a2, a3);
    r.u[2] = pack_bf16(a4, a5); r.u[3] = pack_bf16(a6, a7);
    return r.v;
}
__device__ __forceinline__ bf16x8 words4(unsigned int w0, unsigned int w1,
                                         unsigned int w2, unsigned int w3) {
    union { bf16x8 v; unsigned int u[4]; } r;
    r.u[0] = w0; r.u[1] = w1; r.u[2] = w2; r.u[3] = w3;
    return r.v;
}

// Tiled bf16 layout for V and acc buffers:
//   elem addr = ((b*1024 + (n>>5))*4 + ((n>>3)&3))*512 + c*8 + (n&7)
// -> an MFMA B-frag read (fixed n-octet across 32 c's) is 512B contiguous.

// ---------------- kernel 1: QKV projection as MFMA GEMM ----------------
__global__ __launch_bounds__(256) void qkv_kernel(
    const float* __restrict__ x,
    const float* __restrict__ Wq, const float* __restrict__ bq,
    const float* __restrict__ Wk, const float* __restrict__ bk,
    const float* __restrict__ Wv, const float* __restrict__ bv,
    unsigned short* __restrict__ qout, unsigned short* __restrict__ kout,
    unsigned short* __restrict__ vout)
{
    const int t = threadIdx.x;
    const int lane = t & 63, wv = t >> 6;
    const int a = lane & 15, g = lane >> 4;

    bf16x8 wf[5][2];
    #pragma unroll
    for (int T = 0; T < 5; ++T) {
        const float* wrow;
        float scale = 1.f;
        if (T == 0) {
            if (a < 8) { wrow = Wq + a*CC; scale = LOG2E; }
            else       { wrow = Wk + (a-8)*CC; }
        } else {
            wrow = Wv + ((T-1)*16 + a)*CC;
        }
        #pragma unroll
        for (int h = 0; h < 2; ++h) {
            float4 w0 = *(const float4*)(wrow + h*32 + g*8);
            float4 w1 = *(const float4*)(wrow + h*32 + g*8 + 4);
            wf[T][h] = pack8(w0.x*scale, w0.y*scale, w0.z*scale, w0.w*scale,
                             w1.x*scale, w1.y*scale, w1.z*scale, w1.w*scale);
        }
    }
    f32x4 bias[5];
    {
        const int r = g*4;
        #pragma unroll
        for (int u = 0; u < 4; ++u) {
            int rr = r + u;
            bias[0][u] = (rr < 8) ? bq[rr]*LOG2E : bk[rr-8];
        }
        #pragma unroll
        for (int T = 1; T < 5; ++T)
            #pragma unroll
            for (int u = 0; u < 4; ++u)
                bias[T][u] = bv[(T-1)*16 + r + u];
    }

    const int wave_id = blockIdx.x*4 + wv;
    #pragma unroll 1
    for (int it = 0; it < 2; ++it) {
        const int chunk = wave_id + it*4096;
        const int b = chunk >> 11;
        const int n0 = (chunk & 2047) * 16;
        const int n = n0 + a;
        const float* xcol = x + (size_t)b*CC*NN + n;

        float xv0[8], xv1[8];
        #pragma unroll
        for (int u = 0; u < 8; ++u) xv0[u] = xcol[(size_t)(g*8 + u)*NN];
        #pragma unroll
        for (int u = 0; u < 8; ++u) xv1[u] = xcol[(size_t)(32 + g*8 + u)*NN];
        bf16x8 xb0 = pack8(xv0[0],xv0[1],xv0[2],xv0[3],xv0[4],xv0[5],xv0[6],xv0[7]);
        bf16x8 xb1 = pack8(xv1[0],xv1[1],xv1[2],xv1[3],xv1[4],xv1[5],xv1[6],xv1[7]);

        f32x4 acc[5];
        #pragma unroll
        for (int T = 0; T < 5; ++T) {
            acc[T] = __builtin_amdgcn_mfma_f32_16x16x32_bf16(wf[T][0], xb0, bias[T], 0, 0, 0);
            acc[T] = __builtin_amdgcn_mfma_f32_16x16x32_bf16(wf[T][1], xb1, acc[T], 0, 0, 0);
        }

        {
            unsigned int lo = pack_bf16(acc[0][0], acc[0][1]);
            unsigned int hi = pack_bf16(acc[0][2], acc[0][3]);
            unsigned short* base = ((g < 2) ? qout : kout) + ((size_t)b*NN + n)*8 + (g & 1)*4;
            *(int2*)base = make_int2((int)lo, (int)hi);
        }
        // v: tiled layout [b][n>>5][(n>>3)&3][c][n&7]
        unsigned short* vtb = vout + (((size_t)b*1024 + (n>>5))*4 + ((n>>3)&3))*512 + (n&7);
        #pragma unroll
        for (int T = 1; T < 5; ++T) {
            #pragma unroll
            for (int u = 0; u < 4; ++u) {
                const int e = (T-1)*16 + g*4 + u;
                vtb[e*8] = to_bf16(acc[T][u]);
            }
        }
    }
}

// ---------------- kernel 2: windowed attention, 32x32x16 MFMA ----------------
// REGISTER-DIET round: R15 structure (2-wave blocks, zero LDS, no barriers,
// tiled V) but total unified VGPR+AGPR forced <= 128 via __launch_bounds__(128,4)
// -> 4 waves/SIMD instead of the hidden-AGPR ~2-3 cap of R8-R15.
// Diet: no V prefetch (L2-resident, TLP hides); exp computed IN PLACE on E.
__global__ __launch_bounds__(128, 4) void attn_kernel(
    const unsigned short* __restrict__ qg, const unsigned short* __restrict__ kg,
    const unsigned short* __restrict__ vg,
    unsigned short* __restrict__ accE, unsigned short* __restrict__ accO)
{
    const int t = threadIdx.x;
    const int lane = t & 63, wv = t >> 6;
    const int l31 = lane & 31, hi = lane >> 5;
    int bid = (blockIdx.x & 7)*508 + (blockIdx.x >> 3);   // XCD bijective swizzle (8x508)
    const int oct = bid & 7; bid >>= 3;                   // 8 blocks per window
    const int w = bid % NWIN, b = bid / NWIN;
    const int nwin = STR * w;
    const int i0 = oct*64 + wv*32;

    const unsigned short* qbase = qg + ((size_t)b*NN + nwin + i0)*8;
    const unsigned short* kbase = kg + ((size_t)b*NN + nwin)*8;
    // V frag (ct, sl) at tile jt: vt + (jt*4 + sl*2)*512 + ct*256
    const unsigned short* vt = vg + (((size_t)b*1024 + 8*w)*4 + 2*hi)*512 + (size_t)l31*8;

    const bf16x8 zf = {};
    // Q B-frag: col i = l31, k = d = 8*hi+e; hi half zeroed (d-pad annihilates)
    bf16x8 qf;
    {
        bf16x8 raw = *(const bf16x8*)(qbase + (size_t)l31*8);
        qf = hi ? zf : raw;
    }

    f32x16 acc[2] = {};    // [ct]
    float2 rsum2 = make_float2(0.f, 0.f);

    // prefetch jt=0 K frag only (V not prefetched: register diet)
    bf16x8 kc = *(const bf16x8*)(kbase + (size_t)l31*8);

    #pragma unroll 2
    for (int jt = 0; jt < 16; ++jt) {
        // next tile's K (renamed by unroll)
        bf16x8 kn = kc;
        if (jt < 15) kn = *(const bf16x8*)(kbase + (size_t)(jt*32 + 32 + l31)*8);
        // this tile's V frags (issued early; L2 latency hidden by E/exp phase + TLP)
        bf16x8 vc[2][2];
        #pragma unroll
        for (int ct = 0; ct < 2; ++ct)
            #pragma unroll
            for (int sl = 0; sl < 2; ++sl)
                vc[ct][sl] = *(const bf16x8*)(vt + (size_t)(jt*4 + sl*2)*512 + ct*256);

        const f32x16 z16 = {};
        f32x16 E = __builtin_amdgcn_mfma_f32_32x32x16_bf16(kc, qf, z16, 0, 0, 0);
        // exp IN PLACE (E regs reused; no separate p[16])
        #pragma unroll
        for (int r = 0; r < 16; ++r) E[r] = fast_exp2(E[r]);
        float2 s0 = make_float2(E[0],  E[1])  + make_float2(E[2],  E[3]);
        float2 s1 = make_float2(E[4],  E[5])  + make_float2(E[6],  E[7]);
        float2 s2 = make_float2(E[8],  E[9])  + make_float2(E[10], E[11]);
        float2 s3 = make_float2(E[12], E[13]) + make_float2(E[14], E[15]);
        rsum2 += (s0 + s1) + (s2 + s3);
        unsigned int wd[8];
        #pragma unroll
        for (int tw = 0; tw < 8; ++tw) wd[tw] = pack_bf16(E[2*tw], E[2*tw+1]);
        unsigned int F0 = wd[0], F2 = wd[2]; plswap(F0, F2);
        unsigned int F1 = wd[1], F3 = wd[3]; plswap(F1, F3);
        unsigned int G0 = wd[4], G2 = wd[6]; plswap(G0, G2);
        unsigned int G1 = wd[5], G3 = wd[7]; plswap(G1, G3);
        bf16x8 pa0 = words4(F0, F1, F2, F3);   // k-slab j+0..15
        bf16x8 pa1 = words4(G0, G1, G2, G3);   // k-slab j+16..31
        #pragma unroll
        for (int ct = 0; ct < 2; ++ct) {
            acc[ct] = __builtin_amdgcn_mfma_f32_32x32x16_bf16(pa0, vc[ct][0], acc[ct], 0, 0, 0);
            acc[ct] = __builtin_amdgcn_mfma_f32_32x32x16_bf16(pa1, vc[ct][1], acc[ct], 0, 0, 0);
        }
        kc = kn;
    }

    // ---- normalization: combine hi/lo j-halves; broadcast 1/r via shfl (no LDS) ----
    float r = rsum2.x + rsum2.y;
    r += __shfl_xor(r, 32);
    const float inv = 1.f / r;            // lane's own col i = l31
    f32x4 invv[4];
    #pragma unroll
    for (int g = 0; g < 4; ++g)
        #pragma unroll
        for (int u = 0; u < 4; ++u)
            invv[g][u] = __shfl(inv, 8*g + 4*hi + u);

    // tiled store: i_local = u + 8*g + 4*hi -> addr = (Tb + g)*512 + c*8 + 4*hi + u
    unsigned short* ob = ((w & 1) ? accO : accE)
        + ((size_t)b*1024 + ((nwin + i0) >> 5))*4*512 + 4*hi;
    #pragma unroll
    for (int ct = 0; ct < 2; ++ct) {
        unsigned short* cbase = ob + (ct*32 + l31)*8;
        #pragma unroll
        for (int g = 0; g < 4; ++g) {
            float a0 = acc[ct][4*g+0] * invv[g][0];
            float a1 = acc[ct][4*g+1] * invv[g][1];
            float a2 = acc[ct][4*g+2] * invv[g][2];
            float a3 = acc[ct][4*g+3] * invv[g][3];
            int2 pw = make_int2((int)pack_bf16(a0, a1), (int)pack_bf16(a2, a3));
            *(int2*)(cbase + (size_t)g*512) = pw;
        }
    }
}

// ---------------- kernel 3: combine + 2:1 maxpool ----------------
__global__ __launch_bounds__(256) void final_kernel(
    const float* __restrict__ x,
    const unsigned short* __restrict__ accE, const unsigned short* __restrict__ accO,
    const float* __restrict__ gamma, float* __restrict__ out)
{
    const size_t tid = (size_t)blockIdx.x*256 + threadIdx.x;  // B*C*N/8 threads
    const size_t base = tid*8;                                 // logical [b][c][n]
    const int n = (int)(base & (NN-1));
    const int c = (int)((base >> 15) & (CC-1));
    const int b = (int)(base >> 21);
    const float g = gamma[0];
    // tiled acc address for (b, c, n..n+7)
    const size_t tadr = (((size_t)b*1024 + (n >> 5))*4 + ((n >> 3) & 3))*512 + c*8;

    float xv[8];
    *(float4*)&xv[0] = *(const float4*)&x[base];
    *(float4*)&xv[4] = *(const float4*)&x[base+4];
    int4 aeq = *(const int4*)&accE[tadr];
    const unsigned int* ae = (const unsigned int*)&aeq;

    float s[8];
    if (n >= STR && n < NN - STR) {
        int4 aoq = *(const int4*)&accO[tadr];
        const unsigned int* ao = (const unsigned int*)&aoq;
        #pragma unroll
        for (int u = 0; u < 4; ++u) {
            float e0 = bf2f((unsigned short)(ae[u] & 0xffff));
            float e1 = bf2f((unsigned short)(ae[u] >> 16));
            float o0 = bf2f((unsigned short)(ao[u] & 0xffff));
            float o1 = bf2f((unsigned short)(ao[u] >> 16));
            s[2*u]   = fmaf(g, (e0 + o0)*0.5f, xv[2*u]);
            s[2*u+1] = fmaf(g, (e1 + o1)*0.5f, xv[2*u+1]);
        }
    } else {
        #pragma unroll
        for (int u = 0; u < 4; ++u) {
            float e0 = bf2f((unsigned short)(ae[u] & 0xffff));
            float e1 = bf2f((unsigned short)(ae[u] >> 16));
            s[2*u]   = fmaf(g, e0, xv[2*u]);
            s[2*u+1] = fmaf(g, e1, xv[2*u+1]);
        }
    }
    float4 o = make_float4(fmaxf(s[0], s[1]), fmaxf(s[2], s[3]),
                           fmaxf(s[4], s[5]), fmaxf(s[6], s[7]));
    *(float4*)&out[tid*4] = o;
}

extern "C" void kernel_launch(void* const* d_in, const int* in_sizes, int n_in,
                              void* d_out, int out_size, void* d_ws, size_t ws_size,
                              hipStream_t stream)
{
    const float* x    = (const float*)d_in[0];
    const float* Wq   = (const float*)d_in[1];
    const float* bq   = (const float*)d_in[2];
    const float* Wk   = (const float*)d_in[3];
    const float* bk   = (const float*)d_in[4];
    const float* Wv   = (const float*)d_in[5];
    const float* bv   = (const float*)d_in[6];
    const float* gamma= (const float*)d_in[7];

    unsigned short* q    = (unsigned short*)d_ws;
    unsigned short* k    = q + (size_t)BB*NN*DD;
    unsigned short* v    = k + (size_t)BB*NN*DD;
    unsigned short* accE = v + (size_t)BB*CC*NN;
    unsigned short* accO = accE + (size_t)BB*CC*NN;
    float* out = (float*)d_out;

    qkv_kernel<<<1024, 256, 0, stream>>>(x, Wq, bq, Wk, bk, Wv, bv, q, k, v);
    attn_kernel<<<BB*NWIN*8, 128, 0, stream>>>(q, k, v, accE, accO);
    final_kernel<<<BB*CC*NN/8/256, 256, 0, stream>>>(x, accE, accO, gamma, out);
}